// Round 4
// baseline (497.995 us; speedup 1.0000x reference)
//
#include <hip/hip_runtime.h>
#include <hip/hip_bf16.h>
#include <math.h>

// Problem: B=32, L=2048, E=512, Q=512, K=E+Q=1024, M=B*L=65536
// out = [applied (32*512 f32), weights (32*2048 f32)]

typedef __attribute__((ext_vector_type(8))) short bf16x8;
typedef __attribute__((ext_vector_type(4))) float f32x4;

#define BDIM 32
#define LDIM 2048
#define EDIM 512
#define QDIM 512
#define KDIM 1024
#define MDIM (BDIM * LDIM)

#define BM 128
#define BN 128
#define BK 64
#define LDS_STRIDE (BK + 8) // 72 bf16 = 144B rows

// exact RNE pack: v_cvt_pk_bf16_f32 on gfx950 (1 inst / 2 elems)
__device__ inline unsigned int pack2(float lo, float hi) {
    __hip_bfloat162 h = __float22bfloat162_rn(float2{lo, hi});
    unsigned int u;
    __builtin_memcpy(&u, &h, sizeof(u));
    return u;
}

// tanh via hw v_exp_f32: 1 - 2/(e^{2x}+1); saturates correctly at +-inf
__device__ inline float fast_tanh(float x) {
    float e = __expf(2.0f * x);
    return 1.0f - 2.0f / (e + 1.0f);
}

__global__ __launch_bounds__(256) void scores_kernel(
    const float* __restrict__ emb, const float* __restrict__ query,
    const float* __restrict__ W, const float* __restrict__ b_attn,
    const float* __restrict__ v_w, float* __restrict__ scores)
{
    __shared__ unsigned short As[BM][LDS_STRIDE];
    __shared__ unsigned short Bs[BN][LDS_STRIDE];

    const int tid = threadIdx.x;
    const int bid = blockIdx.x;
    // XCD-aware: blocks land on XCD (bid % 8). Whole mtile groups per XCD so
    // the 4 ntile-sharers of one A-tile hit the same 4MB L2. (r2: FETCH 545->164MB)
    const int xcd = bid & 7;
    const int slot = bid >> 3;            // 0..255 per XCD, in dispatch order
    const int mtile = xcd * 64 + (slot >> 2);
    const int ntile = slot & 3;
    const int m0 = mtile * BM;
    const int n0 = ntile * BN;

    const int lane = tid & 63;
    const int wv = tid >> 6;          // 4 waves
    const int wm = (wv >> 1) * 64;    // wave's 64x64 quadrant
    const int wn = (wv & 1) * 64;
    const int quad = lane >> 4;
    const int ln = lane & 15;

    const int row16 = tid >> 4;       // staging: 16 rows/pass, 16 float4 cols
    const int col4  = (tid & 15) * 4;

    f32x4 acc[4][4];
    #pragma unroll
    for (int i = 0; i < 4; i++)
        #pragma unroll
        for (int j = 0; j < 4; j++)
            acc[i][j] = (f32x4){0.f, 0.f, 0.f, 0.f};

    float4 ra[8], rb[8], na[8], nb[8];

    // ---- preload k0 = 0 ----
    #pragma unroll
    for (int p = 0; p < 8; p++)
        ra[p] = *(const float4*)(query + (size_t)(m0 + p * 16 + row16) * 512 + col4);
    #pragma unroll
    for (int p = 0; p < 8; p++)
        rb[p] = *(const float4*)(W + (size_t)(n0 + p * 16 + row16) * 1024 + col4);

    #pragma unroll 2
    for (int k0 = 0; k0 < KDIM; k0 += BK) {
        // ---- pack current tile (waits on ra/rb loads) + write to LDS ----
        #pragma unroll
        for (int p = 0; p < 8; p++) {
            uint2 pk;
            pk.x = pack2(ra[p].x, ra[p].y);
            pk.y = pack2(ra[p].z, ra[p].w);
            *(uint2*)&As[p * 16 + row16][col4] = pk;
        }
        #pragma unroll
        for (int p = 0; p < 8; p++) {
            uint2 pk;
            pk.x = pack2(rb[p].x, rb[p].y);
            pk.y = pack2(rb[p].z, rb[p].w);
            *(uint2*)&Bs[p * 16 + row16][col4] = pk;
        }
        __syncthreads();

        // ---- issue next tile's global loads (VGPR dest: survives barriers) ----
        const int k1 = k0 + BK;
        if (k1 < KDIM) {
            const float* asrc = (k1 < QDIM) ? query : emb;
            const int koff = k1 & (QDIM - 1);
            #pragma unroll
            for (int p = 0; p < 8; p++)
                na[p] = *(const float4*)(asrc + (size_t)(m0 + p * 16 + row16) * 512 + koff + col4);
            #pragma unroll
            for (int p = 0; p < 8; p++)
                nb[p] = *(const float4*)(W + (size_t)(n0 + p * 16 + row16) * 1024 + k1 + col4);
        }

        // ---- MFMA over current LDS tile ----
        #pragma unroll
        for (int ks = 0; ks < 2; ks++) {
            bf16x8 af[4], bf[4];
            #pragma unroll
            for (int i = 0; i < 4; i++)
                af[i] = *(const bf16x8*)&As[wm + i * 16 + ln][ks * 32 + quad * 8];
            #pragma unroll
            for (int j = 0; j < 4; j++)
                bf[j] = *(const bf16x8*)&Bs[wn + j * 16 + ln][ks * 32 + quad * 8];
            #pragma unroll
            for (int i = 0; i < 4; i++)
                #pragma unroll
                for (int j = 0; j < 4; j++)
                    acc[i][j] = __builtin_amdgcn_mfma_f32_16x16x32_bf16(af[i], bf[j], acc[i][j], 0, 0, 0);
        }
        __syncthreads();

        // ping-pong (renamed away under unroll 2)
        #pragma unroll
        for (int p = 0; p < 8; p++) { ra[p] = na[p]; rb[p] = nb[p]; }
    }

    // ---- fused epilogue: sum_n tanh(x + b[n]) * v_w[n], reduce over 16 cols ----
    float bj[4], vj[4];
    #pragma unroll
    for (int j = 0; j < 4; j++) {
        const int n = n0 + wn + j * 16 + ln;
        bj[j] = b_attn[n];
        vj[j] = v_w[n];
    }
    #pragma unroll
    for (int i = 0; i < 4; i++) {
        #pragma unroll
        for (int r = 0; r < 4; r++) {
            float s = 0.f;
            #pragma unroll
            for (int j = 0; j < 4; j++)
                s += fast_tanh(acc[i][j][r] + bj[j]) * vj[j];
            #pragma unroll
            for (int off = 1; off < 16; off <<= 1)
                s += __shfl_xor(s, off, 64);
            if (ln == 0)
                atomicAdd(&scores[m0 + wm + i * 16 + quad * 4 + r], s);
        }
    }
}

__global__ __launch_bounds__(256) void softmax_apply_kernel(
    const float* __restrict__ emb, const float* __restrict__ scores,
    float* __restrict__ out_applied, float* __restrict__ out_weights)
{
    const int b = blockIdx.x >> 5;      // 32 L-chunks of 64 rows
    const int chunk = blockIdx.x & 31;
    const int l0 = chunk * 64;
    const int tid = threadIdx.x;
    const float* srow = scores + b * LDIM;

    __shared__ float red[4];
    __shared__ float wls[64];
    __shared__ float partial[128 * 4];

    // redundant-but-deterministic softmax stats over full row (8 KB, L2-hot)
    float mx = -1e30f;
    #pragma unroll
    for (int t = 0; t < 8; t++) mx = fmaxf(mx, srow[tid + t * 256]);
    #pragma unroll
    for (int off = 1; off < 64; off <<= 1) mx = fmaxf(mx, __shfl_xor(mx, off, 64));
    if ((tid & 63) == 0) red[tid >> 6] = mx;
    __syncthreads();
    mx = fmaxf(fmaxf(red[0], red[1]), fmaxf(red[2], red[3]));

    float sm = 0.f;
    #pragma unroll
    for (int t = 0; t < 8; t++) sm += expf(srow[tid + t * 256] - mx);
    #pragma unroll
    for (int off = 1; off < 64; off <<= 1) sm += __shfl_xor(sm, off, 64);
    __syncthreads();
    if ((tid & 63) == 0) red[tid >> 6] = sm;
    __syncthreads();
    sm = red[0] + red[1] + red[2] + red[3];
    const float inv = 1.f / sm;

    if (tid < 64) {
        const float w = expf(srow[l0 + tid] - mx) * inv;
        wls[tid] = w;
        out_weights[(size_t)b * LDIM + l0 + tid] = w;
    }
    __syncthreads();

    // weighted sum over 64 rows: two row-halves (waves 0-1 / 2-3) each do 32
    // strided rows with float4 loads, then LDS cross-half reduce + atomics.
    const int half = tid >> 7;          // wave-uniform
    const int cg = tid & 127;           // column group of 4 floats
    float4 acc = {0.f, 0.f, 0.f, 0.f};
    const float* ebase = emb + ((size_t)b * LDIM + l0 + half) * EDIM + cg * 4;
    #pragma unroll 8
    for (int i = 0; i < 32; i++) {
        const float4 v = *(const float4*)(ebase + (size_t)2 * i * EDIM);
        const float w = wls[half + 2 * i];
        acc.x += w * v.x;
        acc.y += w * v.y;
        acc.z += w * v.z;
        acc.w += w * v.w;
    }
    if (half == 1) *(float4*)&partial[cg * 4] = acc;
    __syncthreads();
    if (half == 0) {
        const float4 p = *(const float4*)&partial[cg * 4];
        float* dst = out_applied + b * EDIM + cg * 4;
        atomicAdd(dst + 0, acc.x + p.x);
        atomicAdd(dst + 1, acc.y + p.y);
        atomicAdd(dst + 2, acc.z + p.z);
        atomicAdd(dst + 3, acc.w + p.w);
    }
}

extern "C" void kernel_launch(void* const* d_in, const int* in_sizes, int n_in,
                              void* d_out, int out_size, void* d_ws, size_t ws_size,
                              hipStream_t stream) {
    const float* emb    = (const float*)d_in[0];
    const float* query  = (const float*)d_in[1];
    const float* W      = (const float*)d_in[2];
    const float* b_attn = (const float*)d_in[3];
    const float* v_w    = (const float*)d_in[4];

    float* out     = (float*)d_out;
    float* applied = out;                 // 32*512 floats
    float* weights = out + BDIM * EDIM;   // 32*2048 floats
    float* scores  = (float*)d_ws;        // 65536 floats = 256 KB scratch

    (void)hipMemsetAsync(scores, 0, (size_t)MDIM * sizeof(float), stream);
    (void)hipMemsetAsync(applied, 0, (size_t)BDIM * EDIM * sizeof(float), stream);

    // grid = (M/BM) * (N/BN) = 512 * 4 = 2048 blocks
    scores_kernel<<<2048, 256, 0, stream>>>(emb, query, W, b_attn, v_w, scores);

    // grid = B * 32 chunks = 1024 blocks
    softmax_apply_kernel<<<1024, 256, 0, stream>>>(emb, scores, applied, weights);
}

// Round 5
// 451.158 us; speedup vs baseline: 1.1038x; 1.1038x over previous
//
#include <hip/hip_runtime.h>
#include <hip/hip_bf16.h>
#include <math.h>

// Problem: B=32, L=2048, E=512, Q=512, K=E+Q=1024, M=B*L=65536
// out = [applied (32*512 f32), weights (32*2048 f32)]
//
// r4 lesson: register prefetch halved occupancy (VGPR 96->140) and REGRESSED
// 210->295us. r5 structure: pre-convert fp32->bf16 once (separate HBM-bound
// pass), then m97-style GEMM with global_load_lds (no staging VALU at all).

typedef __attribute__((ext_vector_type(8))) short bf16x8;
typedef __attribute__((ext_vector_type(4))) float f32x4;
typedef unsigned short u16;

#define BDIM 32
#define LDIM 2048
#define EDIM 512
#define QDIM 512
#define KDIM 1024
#define MDIM (BDIM * LDIM)

// exact RNE pack: v_cvt_pk_bf16_f32 on gfx950 (1 inst / 2 elems)
__device__ inline unsigned int pack2(float lo, float hi) {
    __hip_bfloat162 h = __float22bfloat162_rn(float2{lo, hi});
    unsigned int u;
    __builtin_memcpy(&u, &h, sizeof(u));
    return u;
}

// tanh via hw v_exp_f32: 1 - 2/(e^{2x}+1); saturates correctly at +-inf
__device__ inline float fast_tanh(float x) {
    float e = __expf(2.0f * x);
    return 1.0f - 2.0f / (e + 1.0f);
}

#define GLD_LDS16(g, l) \
    __builtin_amdgcn_global_load_lds( \
        (__attribute__((address_space(1))) const void*)(g), \
        (__attribute__((address_space(3))) void*)(l), 16, 0, 0)

// ---------------------------------------------------------------------------
// Pass 0: convert [query|emb] -> Abf (M x 1024 bf16) and W -> Wbf (512 x 1024)
// Rows 0..65535 = A (concat), rows 65536..66047 = W. 2064 blocks x 32 rows.
// HBM-bound: 270 MB read + 135 MB write.
// ---------------------------------------------------------------------------
__global__ __launch_bounds__(256) void convert_kernel(
    const float* __restrict__ emb, const float* __restrict__ query,
    const float* __restrict__ W, u16* __restrict__ Abf, u16* __restrict__ Wbf)
{
    const int tid = threadIdx.x;
    const int col = tid * 4;                 // 256 threads x float4 = one row
    const int r0 = blockIdx.x * 32;
    #pragma unroll 4
    for (int i = 0; i < 32; i++) {
        const int row = r0 + i;
        float4 v;
        u16* dst;
        if (row < MDIM) {
            const float* src = (col < QDIM)
                ? (query + (size_t)row * QDIM + col)
                : (emb + (size_t)row * EDIM + (col - QDIM));
            v = *(const float4*)src;
            dst = Abf + (size_t)row * KDIM + col;
        } else {
            v = *(const float4*)(W + (size_t)(row - MDIM) * KDIM + col);
            dst = Wbf + (size_t)(row - MDIM) * KDIM + col;
        }
        uint2 pk;
        pk.x = pack2(v.x, v.y);
        pk.y = pack2(v.z, v.w);
        *(uint2*)dst = pk;
    }
}

// ---------------------------------------------------------------------------
// Pass 1: scores = sum_n tanh((A @ W^T)[m,n] + b[n]) * v[n]
// m97 structure: 128x128x64 tile, global_load_lds width=16, 2-barrier K-loop.
// LDS layout: [row][kgroup] row-major, 64 bf16 = 128B rows, with XOR swizzle:
// LDS slot g holds global k-group g ^ (row&7)  (spreads ds_read_b128 over all
// 32 banks). Staging lane constants make the swizzle free: lane reads global
// group (lane&7)^(lane>>3), hardware writes LDS at lane*16.
// ---------------------------------------------------------------------------
__global__ __launch_bounds__(256) void scores_mfma_kernel(
    const u16* __restrict__ Abf, const u16* __restrict__ Wbf,
    const float* __restrict__ b_attn, const float* __restrict__ v_w,
    float* __restrict__ scores)
{
    __shared__ u16 As[128 * 64];
    __shared__ u16 Bs[128 * 64];

    const int tid = threadIdx.x;
    const int bid = blockIdx.x;
    // XCD-aware swizzle (r2: FETCH 545->164MB): the 4 ntile-sharers of one
    // A-tile land on the same XCD's 4MB L2.
    const int xcd = bid & 7;
    const int slot = bid >> 3;
    const int mtile = xcd * 64 + (slot >> 2);
    const int ntile = slot & 3;
    const int m0 = mtile * 128;
    const int n0 = ntile * 128;

    const int lane = tid & 63;
    const int wv = tid >> 6;          // 4 waves
    const int wm = (wv >> 1) * 64;    // wave's 64x64 quadrant
    const int wn = (wv & 1) * 64;
    const int quad = lane >> 4;
    const int ln = lane & 15;

    // staging lane constants: wave wv stages rows wv*32..wv*32+31 (4 issues x 8 rows)
    const int srow = lane >> 3;                 // 0..7 within an issue
    const int sg = (lane & 7) ^ srow;           // swizzled global k-group

    const u16* ab = Abf + (size_t)(m0 + wv * 32 + srow) * KDIM + sg * 8;
    const u16* bb = Wbf + (size_t)(n0 + wv * 32 + srow) * KDIM + sg * 8;
    u16* asl = As + (wv * 4) * 512;             // + qq*512, wave-uniform
    u16* bsl = Bs + (wv * 4) * 512;

    f32x4 acc[4][4];
    #pragma unroll
    for (int i = 0; i < 4; i++)
        #pragma unroll
        for (int j = 0; j < 4; j++)
            acc[i][j] = (f32x4){0.f, 0.f, 0.f, 0.f};

    for (int k0 = 0; k0 < KDIM; k0 += 64) {
        #pragma unroll
        for (int qq = 0; qq < 4; qq++) {
            GLD_LDS16(ab + (size_t)qq * 8 * KDIM + k0, asl + qq * 512);
            GLD_LDS16(bb + (size_t)qq * 8 * KDIM + k0, bsl + qq * 512);
        }
        __syncthreads();

        #pragma unroll
        for (int ks = 0; ks < 2; ks++) {
            bf16x8 af[4], bfr[4];
            #pragma unroll
            for (int i = 0; i < 4; i++) {
                const int r = wm + i * 16 + ln;
                af[i] = *(const bf16x8*)&As[r * 64 + (((ks * 4 + quad) ^ (ln & 7)) * 8)];
            }
            #pragma unroll
            for (int j = 0; j < 4; j++) {
                const int r = wn + j * 16 + ln;
                bfr[j] = *(const bf16x8*)&Bs[r * 64 + (((ks * 4 + quad) ^ (ln & 7)) * 8)];
            }
            #pragma unroll
            for (int i = 0; i < 4; i++)
                #pragma unroll
                for (int j = 0; j < 4; j++)
                    acc[i][j] = __builtin_amdgcn_mfma_f32_16x16x32_bf16(af[i], bfr[j], acc[i][j], 0, 0, 0);
        }
        __syncthreads();
    }

    // fused epilogue: sum_n tanh(x + b[n]) * v_w[n], reduce over 16 cols
    float bj[4], vj[4];
    #pragma unroll
    for (int j = 0; j < 4; j++) {
        const int n = n0 + wn + j * 16 + ln;
        bj[j] = b_attn[n];
        vj[j] = v_w[n];
    }
    #pragma unroll
    for (int i = 0; i < 4; i++) {
        #pragma unroll
        for (int r = 0; r < 4; r++) {
            float s = 0.f;
            #pragma unroll
            for (int j = 0; j < 4; j++)
                s += fast_tanh(acc[i][j][r] + bj[j]) * vj[j];
            #pragma unroll
            for (int off = 1; off < 16; off <<= 1)
                s += __shfl_xor(s, off, 64);
            if (ln == 0)
                atomicAdd(&scores[m0 + wm + i * 16 + quad * 4 + r], s);
        }
    }
}

// ---------------------------------------------------------------------------
// Fallback (ws too small): r2's fused-convert GEMM (210us) — verbatim.
// ---------------------------------------------------------------------------
#define LDS_STRIDE 72
__global__ __launch_bounds__(256) void scores_fused_kernel(
    const float* __restrict__ emb, const float* __restrict__ query,
    const float* __restrict__ W, const float* __restrict__ b_attn,
    const float* __restrict__ v_w, float* __restrict__ scores)
{
    __shared__ u16 As[128][LDS_STRIDE];
    __shared__ u16 Bs[128][LDS_STRIDE];

    const int tid = threadIdx.x;
    const int bid = blockIdx.x;
    const int xcd = bid & 7;
    const int slot = bid >> 3;
    const int mtile = xcd * 64 + (slot >> 2);
    const int ntile = slot & 3;
    const int m0 = mtile * 128;
    const int n0 = ntile * 128;

    const int lane = tid & 63;
    const int wv = tid >> 6;
    const int wm = (wv >> 1) * 64;
    const int wn = (wv & 1) * 64;
    const int quad = lane >> 4;
    const int ln = lane & 15;

    const int row16 = tid >> 4;
    const int col4 = (tid & 15) * 4;

    f32x4 acc[4][4];
    #pragma unroll
    for (int i = 0; i < 4; i++)
        #pragma unroll
        for (int j = 0; j < 4; j++)
            acc[i][j] = (f32x4){0.f, 0.f, 0.f, 0.f};

    for (int k0 = 0; k0 < KDIM; k0 += 64) {
        const float* asrc = (k0 < QDIM) ? query : emb;
        const int koff = k0 & (QDIM - 1);
        #pragma unroll
        for (int p = 0; p < 8; p++) {
            const float4 v = *(const float4*)(asrc + (size_t)(m0 + p * 16 + row16) * 512 + koff + col4);
            uint2 pk;
            pk.x = pack2(v.x, v.y);
            pk.y = pack2(v.z, v.w);
            *(uint2*)&As[p * 16 + row16][col4] = pk;
        }
        #pragma unroll
        for (int p = 0; p < 8; p++) {
            const float4 v = *(const float4*)(W + (size_t)(n0 + p * 16 + row16) * 1024 + k0 + col4);
            uint2 pk;
            pk.x = pack2(v.x, v.y);
            pk.y = pack2(v.z, v.w);
            *(uint2*)&Bs[p * 16 + row16][col4] = pk;
        }
        __syncthreads();

        #pragma unroll
        for (int ks = 0; ks < 2; ks++) {
            bf16x8 af[4], bfr[4];
            #pragma unroll
            for (int i = 0; i < 4; i++)
                af[i] = *(const bf16x8*)&As[wm + i * 16 + ln][ks * 32 + quad * 8];
            #pragma unroll
            for (int j = 0; j < 4; j++)
                bfr[j] = *(const bf16x8*)&Bs[wn + j * 16 + ln][ks * 32 + quad * 8];
            #pragma unroll
            for (int i = 0; i < 4; i++)
                #pragma unroll
                for (int j = 0; j < 4; j++)
                    acc[i][j] = __builtin_amdgcn_mfma_f32_16x16x32_bf16(af[i], bfr[j], acc[i][j], 0, 0, 0);
        }
        __syncthreads();
    }

    float bj[4], vj[4];
    #pragma unroll
    for (int j = 0; j < 4; j++) {
        const int n = n0 + wn + j * 16 + ln;
        bj[j] = b_attn[n];
        vj[j] = v_w[n];
    }
    #pragma unroll
    for (int i = 0; i < 4; i++) {
        #pragma unroll
        for (int r = 0; r < 4; r++) {
            float s = 0.f;
            #pragma unroll
            for (int j = 0; j < 4; j++)
                s += fast_tanh(acc[i][j][r] + bj[j]) * vj[j];
            #pragma unroll
            for (int off = 1; off < 16; off <<= 1)
                s += __shfl_xor(s, off, 64);
            if (ln == 0)
                atomicAdd(&scores[m0 + wm + i * 16 + quad * 4 + r], s);
        }
    }
}

__global__ __launch_bounds__(256) void softmax_apply_kernel(
    const float* __restrict__ emb, const float* __restrict__ scores,
    float* __restrict__ out_applied, float* __restrict__ out_weights)
{
    const int b = blockIdx.x >> 5;      // 32 L-chunks of 64 rows
    const int chunk = blockIdx.x & 31;
    const int l0 = chunk * 64;
    const int tid = threadIdx.x;
    const float* srow = scores + b * LDIM;

    __shared__ float red[4];
    __shared__ float wls[64];
    __shared__ float partial[128 * 4];

    float mx = -1e30f;
    #pragma unroll
    for (int t = 0; t < 8; t++) mx = fmaxf(mx, srow[tid + t * 256]);
    #pragma unroll
    for (int off = 1; off < 64; off <<= 1) mx = fmaxf(mx, __shfl_xor(mx, off, 64));
    if ((tid & 63) == 0) red[tid >> 6] = mx;
    __syncthreads();
    mx = fmaxf(fmaxf(red[0], red[1]), fmaxf(red[2], red[3]));

    float sm = 0.f;
    #pragma unroll
    for (int t = 0; t < 8; t++) sm += expf(srow[tid + t * 256] - mx);
    #pragma unroll
    for (int off = 1; off < 64; off <<= 1) sm += __shfl_xor(sm, off, 64);
    __syncthreads();
    if ((tid & 63) == 0) red[tid >> 6] = sm;
    __syncthreads();
    sm = red[0] + red[1] + red[2] + red[3];
    const float inv = 1.f / sm;

    if (tid < 64) {
        const float w = expf(srow[l0 + tid] - mx) * inv;
        wls[tid] = w;
        out_weights[(size_t)b * LDIM + l0 + tid] = w;
    }
    __syncthreads();

    const int half = tid >> 7;
    const int cg = tid & 127;
    float4 acc = {0.f, 0.f, 0.f, 0.f};
    const float* ebase = emb + ((size_t)b * LDIM + l0 + half) * EDIM + cg * 4;
    #pragma unroll 8
    for (int i = 0; i < 32; i++) {
        const float4 v = *(const float4*)(ebase + (size_t)2 * i * EDIM);
        const float w = wls[half + 2 * i];
        acc.x += w * v.x;
        acc.y += w * v.y;
        acc.z += w * v.z;
        acc.w += w * v.w;
    }
    if (half == 1) *(float4*)&partial[cg * 4] = acc;
    __syncthreads();
    if (half == 0) {
        const float4 p = *(const float4*)&partial[cg * 4];
        float* dst = out_applied + b * EDIM + cg * 4;
        atomicAdd(dst + 0, acc.x + p.x);
        atomicAdd(dst + 1, acc.y + p.y);
        atomicAdd(dst + 2, acc.z + p.z);
        atomicAdd(dst + 3, acc.w + p.w);
    }
}

extern "C" void kernel_launch(void* const* d_in, const int* in_sizes, int n_in,
                              void* d_out, int out_size, void* d_ws, size_t ws_size,
                              hipStream_t stream) {
    const float* emb    = (const float*)d_in[0];
    const float* query  = (const float*)d_in[1];
    const float* W      = (const float*)d_in[2];
    const float* b_attn = (const float*)d_in[3];
    const float* v_w    = (const float*)d_in[4];

    float* out     = (float*)d_out;
    float* applied = out;                 // 32*512 floats
    float* weights = out + BDIM * EDIM;   // 32*2048 floats

    const size_t abf_bytes = (size_t)MDIM * KDIM * sizeof(u16);   // 134.2 MB
    const size_t wbf_bytes = (size_t)EDIM * KDIM * sizeof(u16);   // 1 MB
    const size_t sc_bytes  = (size_t)MDIM * sizeof(float);        // 256 KB
    const bool big_ws = ws_size >= abf_bytes + wbf_bytes + sc_bytes;

    if (big_ws) {
        u16* Abf = (u16*)d_ws;
        u16* Wbf = (u16*)((char*)d_ws + abf_bytes);
        float* scores = (float*)((char*)d_ws + abf_bytes + wbf_bytes);

        (void)hipMemsetAsync(scores, 0, sc_bytes, stream);
        (void)hipMemsetAsync(applied, 0, (size_t)BDIM * EDIM * sizeof(float), stream);

        convert_kernel<<<2064, 256, 0, stream>>>(emb, query, W, Abf, Wbf);
        scores_mfma_kernel<<<2048, 256, 0, stream>>>(Abf, Wbf, b_attn, v_w, scores);
        softmax_apply_kernel<<<1024, 256, 0, stream>>>(emb, scores, applied, weights);
    } else {
        float* scores = (float*)d_ws;
        (void)hipMemsetAsync(scores, 0, sc_bytes, stream);
        (void)hipMemsetAsync(applied, 0, (size_t)BDIM * EDIM * sizeof(float), stream);

        scores_fused_kernel<<<2048, 256, 0, stream>>>(emb, query, W, b_attn, v_w, scores);
        softmax_apply_kernel<<<1024, 256, 0, stream>>>(emb, scores, applied, weights);
    }
}